// Round 4
// baseline (278.022 us; speedup 1.0000x reference)
//
#include <hip/hip_runtime.h>

typedef _Float16 f16;
typedef _Float16 f16x8 __attribute__((ext_vector_type(8)));
typedef float f32x4 __attribute__((ext_vector_type(4)));

#define CDIM 256
#define NPIX 9216
#define NSUB 1024
#define NB 8
#define QSTRB 528   // q LDS row stride in bytes (264 f16)

__device__ __forceinline__ f32x4 mfma16(f16x8 a, f16x8 b, f32x4 c) {
  return __builtin_amdgcn_mfma_f32_16x16x32_f16(a, b, c, 0, 0, 0);
}
__device__ __forceinline__ f16x8 ld8(const f16* p) { return *(const f16x8*)p; }

__device__ __forceinline__ void stage16(const void* g, void* l) {
  __builtin_amdgcn_global_load_lds((const __attribute__((address_space(1))) unsigned int*)g,
                                   (__attribute__((address_space(3))) unsigned int*)l, 16, 0, 0);
}
#define S_BARRIER() do { asm volatile("" ::: "memory"); __builtin_amdgcn_s_barrier(); asm volatile("" ::: "memory"); } while (0)
#define WAIT_VM(N) do { asm volatile("s_waitcnt vmcnt(" #N ")" ::: "memory"); __builtin_amdgcn_sched_barrier(0); } while (0)
#define WAIT_LGKM0() do { asm volatile("s_waitcnt lgkmcnt(0)" ::: "memory"); __builtin_amdgcn_sched_barrier(0); } while (0)

// ---------------- K1: fold weights, cast to f16; Wq into per-wave frag layout ----------------
// WqF: frag f = (w*2+ot)*8+ks is 1KB contiguous; lane (q,l15) element at (l15*4+q)*16 bytes,
// holding Wq[o=32w+16ot+l15][c=32ks+8q .. +7].
__global__ void prep_weights(const float* __restrict__ Wq,
                             const float* __restrict__ Wk, const float* __restrict__ bk,
                             const float* __restrict__ Wv, const float* __restrict__ bv,
                             const float* __restrict__ Ws, const float* __restrict__ bs,
                             f16* __restrict__ WqF, f16* __restrict__ Wk2H, f16* __restrict__ Wv2H,
                             float* __restrict__ bk2, float* __restrict__ bv2) {
  int o = blockIdx.x, c = threadIdx.x;
  float ak = 0.f, av = 0.f;
  for (int i = 0; i < CDIM; ++i) {
    float w = Ws[o*CDIM + i];
    ak += w * Wk[i*CDIM + c];
    av += w * Wv[i*CDIM + c];
  }
  Wk2H[o*CDIM + c] = (f16)ak;
  Wv2H[o*CDIM + c] = (f16)av;
  {
    int w = o >> 5, ot = (o >> 4) & 1, l15 = o & 15;
    int ks = c >> 5, q = (c >> 3) & 3, e = c & 7;
    size_t byte = (size_t)(((w*2 + ot)*8 + ks))*1024 + (size_t)(l15*4 + q)*16 + e*2;
    *(f16*)((char*)WqF + byte) = (f16)Wq[o*CDIM + c];
  }
  if (c == 0) {
    float sk = 0.f, sv = 0.f;
    for (int i = 0; i < CDIM; ++i) { float w = Ws[o*CDIM + i]; sk += w*bk[i]; sv += w*bv[i]; }
    bk2[o] = sk + bs[o];
    bv2[o] = sv + bs[o];
  }
}

// ---------------- K2: x[b][c][n] f32 -> xT (swizzled [b][n][c] f16) ----------------
// xT byte layout: row n = 512B; 16B unit u (= c>>3) stored at u ^ (n&7).
__global__ void transpose_x(const float* __restrict__ x, char* __restrict__ xT) {
  __shared__ f16 tile[32][34];   // [c][n]
  int c0 = blockIdx.x * 32, n0 = blockIdx.y * 32, b = blockIdx.z;
  int tx = threadIdx.x, ty = threadIdx.y;
#pragma unroll
  for (int j = 0; j < 4; ++j) {
    int cl = ty + 8*j;
    tile[cl][tx] = (f16)x[(size_t)(b*CDIM + c0 + cl)*NPIX + n0 + tx];
  }
  __syncthreads();
  int tid = ty*32 + tx;
  if (tid < 128) {
    int nl = tid >> 2, u = tid & 3;
    int n = n0 + nl;
    int cu = (c0 >> 3) + u;
    f16x8 v;
#pragma unroll
    for (int e = 0; e < 8; ++e) v[e] = tile[8*u + e][nl];
    size_t byte = (size_t)(b*NPIX + n)*512 + (size_t)((cu ^ (n & 7)) << 4);
    *(f16x8*)(xT + byte) = v;
  }
}

// ---------------- K3: K/V at subsampled pixels -> blocked swizzled layouts ----------------
__global__ __launch_bounds__(256) void compute_kv(
    const char* __restrict__ xT, const f16* __restrict__ Wk2H, const f16* __restrict__ Wv2H,
    const float* __restrict__ bk2, const float* __restrict__ bv2,
    char* __restrict__ kB, char* __restrict__ vB) {
  int m0 = blockIdx.x * 32;
  int b = blockIdx.y;
  int tid = threadIdx.x;
  int w = tid >> 6, lane = tid & 63, l15 = lane & 15, q = lane >> 4;

  const char* xrow[2]; int xn7[2];
#pragma unroll
  for (int mt2 = 0; mt2 < 2; ++mt2) {
    int m = m0 + 16*mt2 + l15;
    int n = 288*(m >> 5) + 3*(m & 31);
    xrow[mt2] = xT + (size_t)(b*NPIX + n)*512;
    xn7[mt2] = n & 7;
  }
  const f16 *kwb[4], *vwb[4];
#pragma unroll
  for (int t = 0; t < 4; ++t) {
    kwb[t] = Wk2H + (size_t)(64*w + 16*t + l15)*CDIM + 8*q;
    vwb[t] = Wv2H + (size_t)(64*w + 16*t + l15)*CDIM + 8*q;
  }
  f32x4 accK[2][4] = {};
  f32x4 accV[4][2] = {};
  for (int ks = 0; ks < 8; ++ks) {
    f16x8 am[2], wk[4], wv[4];
#pragma unroll
    for (int mt2 = 0; mt2 < 2; ++mt2)
      am[mt2] = *(const f16x8*)(xrow[mt2] + (((q + 4*ks) ^ xn7[mt2]) << 4));
#pragma unroll
    for (int t = 0; t < 4; ++t) { wk[t] = ld8(kwb[t] + 32*ks); wv[t] = ld8(vwb[t] + 32*ks); }
#pragma unroll
    for (int mt2 = 0; mt2 < 2; ++mt2)
#pragma unroll
      for (int ot = 0; ot < 4; ++ot) {
        accK[mt2][ot] = mfma16(am[mt2], wk[ot], accK[mt2][ot]);
        accV[ot][mt2] = mfma16(wv[ot], am[mt2], accV[ot][mt2]);
      }
  }
#pragma unroll
  for (int mt2 = 0; mt2 < 2; ++mt2)
#pragma unroll
    for (int ot = 0; ot < 4; ++ot) {
      int cg = 64*w + 16*ot + l15;
      float bo = bk2[cg];
      int ksB = cg >> 5, ci = cg & 31;
#pragma unroll
      for (int r = 0; r < 4; ++r) {
        int m = m0 + 16*mt2 + 4*q + r;
        int u = (((m & 1) << 2) | (ci >> 3)) ^ ((m >> 1) & 7);
        size_t off = (size_t)b*524288 + (size_t)ksB*65536 + (size_t)(m >> 1)*128 + (u << 4) + ((ci & 7) << 1);
        *(f16*)(kB + off) = (f16)(accK[mt2][ot][r] + bo);
      }
    }
#pragma unroll
  for (int ct = 0; ct < 4; ++ct) {
    f32x4 bv4 = *(const f32x4*)(bv2 + 64*w + 16*ct + 4*q);
#pragma unroll
    for (int mt2 = 0; mt2 < 2; ++mt2) {
      int m = m0 + 16*mt2 + l15;
      int ch = m >> 6, mi = m & 63;
#pragma unroll
      for (int r = 0; r < 4; ++r) {
        int cg = 64*w + 16*ct + 4*q + r;
        int u = (mi >> 3) ^ (cg & 7);
        size_t off = (size_t)b*524288 + (size_t)ch*32768 + (size_t)cg*128 + (u << 4) + ((mi & 7) << 1);
        *(f16*)(vB + off) = (f16)(accV[ct][mt2][r] + bv4[r]);
      }
    }
  }
}

// ---------------- K4: fused attention, phase-pipelined (T3+T4+T5) ----------------
__global__ __launch_bounds__(512) void attention(
    const char* __restrict__ xT, const f16* __restrict__ WqF, const float* __restrict__ bq,
    const char* __restrict__ kB, const char* __restrict__ vB,
    const float* __restrict__ x, const float* __restrict__ gamma_p,
    float* __restrict__ out) {
  __shared__ char ring[3*32768];        // K/V chunk ring; ring[2] holds xT tile in phase A
  __shared__ char bufQ[64*QSTRB];       // q tile; after B aliased as P dbuf 2x8KB
  __shared__ float smax[8][64];
  __shared__ float ssum[8][64];

  int bid = blockIdx.x;
  int b = bid & 7;                      // XCD-bijective: 1152 = 8*144, XCD owns one batch
  int ntb = bid >> 3;
  int n0 = ntb * 64;
  int tid = threadIdx.x;
  int w = tid >> 6, lane = tid & 63, l15 = lane & 15, q = lane >> 4;

  const char* xTt = xT + (size_t)(b*NPIX + n0)*512;
  const char* kBb = kB + (size_t)b*524288;
  const char* vBb = vB + (size_t)b*524288;

  // ---- prologue staging: xT -> ring2, K chunk0 -> ring0, K chunk1 -> ring1 ----
  {
    int o = tid * 16;
#pragma unroll
    for (int r = 0; r < 4; ++r) stage16(xTt + o + r*8192, ring + 65536 + o + r*8192);
#pragma unroll
    for (int r = 0; r < 4; ++r) stage16(kBb + o + r*8192, ring + o + r*8192);
#pragma unroll
    for (int r = 0; r < 4; ++r) stage16(kBb + 32768 + o + r*8192, ring + 32768 + o + r*8192);
  }
  // Wq frag loads (coalesced 1KB/frag)
  f16x8 wb[2][8];
  {
    const char* wqf = (const char*)WqF + (size_t)(w*16)*1024 + (size_t)(l15*4 + q)*16;
#pragma unroll
    for (int ot = 0; ot < 2; ++ot)
#pragma unroll
      for (int ks = 0; ks < 8; ++ks) wb[ot][ks] = *(const f16x8*)(wqf + (ot*8 + ks)*1024);
  }
  float bo0 = bq[32*w + l15], bo1 = bq[32*w + 16 + l15];
  WAIT_VM(8);           // xT tile retired (in-order); K0/K1 may remain in flight
  S_BARRIER();

  // ---- Phase A: q = x.Wq^T + bq -> bufQ ----
  {
    f32x4 acc[4][2] = {};
#pragma unroll
    for (int ks = 0; ks < 8; ++ks)
#pragma unroll
      for (int nt = 0; nt < 4; ++nt) {
        int n = 16*nt + l15;
        f16x8 a = *(const f16x8*)(ring + 65536 + n*512 + (((q + 4*ks) ^ (n & 7)) << 4));
        acc[nt][0] = mfma16(a, wb[0][ks], acc[nt][0]);
        acc[nt][1] = mfma16(a, wb[1][ks], acc[nt][1]);
      }
#pragma unroll
    for (int nt = 0; nt < 4; ++nt)
#pragma unroll
      for (int ot = 0; ot < 2; ++ot) {
        int o = 32*w + 16*ot + l15;
        float bo = ot ? bo1 : bo0;
#pragma unroll
        for (int r = 0; r < 4; ++r) {
          int n = 16*nt + 4*q + r;
          *(f16*)(bufQ + n*QSTRB + o*2) = (f16)(acc[nt][ot][r] + bo);
        }
      }
    WAIT_LGKM0();
    S_BARRIER();
  }

  // ---- Phase B: S = q.K^T, 32 phases, 8-MFMA clusters, read-ahead + 3-ring staging ----
  f32x4 S[4][8] = {};
  f16x8 af[2][4], kf[2][2];
#pragma unroll
  for (int nt = 0; nt < 4; ++nt)
    af[0][nt] = *(const f16x8*)(bufQ + (16*nt + l15)*QSTRB + 16*q);
#pragma unroll
  for (int i = 0; i < 2; ++i) {
    int ml = 64*w + 16*i + l15;
    int u = (((ml & 1) << 2) | q) ^ ((ml >> 1) & 7);
    kf[0][i] = *(const f16x8*)(ring + (ml >> 1)*128 + (u << 4));
  }
#pragma unroll
  for (int p = 0; p < 32; ++p) {
    const int j = p >> 1, mp = p & 1, cur = p & 1, nxt = cur ^ 1;
    if (p & 1) WAIT_VM(4);   // chunk j+1 LDS-complete (only chunk j+2's 4 stages newer)
    if (p < 31) {
      const int p1 = p + 1, j2 = p1 >> 1, mp2 = p1 & 1;
      if ((p1 & 3) == 0) {
        const int ks2 = p1 >> 2;
#pragma unroll
        for (int nt = 0; nt < 4; ++nt)
          af[(p1 >> 2) & 1][nt] = *(const f16x8*)(bufQ + (16*nt + l15)*QSTRB + 16*q + 64*ks2);
      }
      const char* kc = ring + (j2 % 3)*32768;
#pragma unroll
      for (int i = 0; i < 2; ++i) {
        int ml = 64*w + 16*(2*mp2 + i) + l15;
        int u = (((ml & 1) << 2) | q) ^ ((ml >> 1) & 7);
        kf[nxt][i] = *(const f16x8*)(kc + (ml >> 1)*128 + (u << 4));
      }
    }
    if (mp == 0 && j + 2 < 16) {
      const char* src = kBb + (size_t)((j + 2) >> 1)*65536 + (size_t)((j + 2) & 1)*32768;
      char* dst = ring + ((j + 2) % 3)*32768;
      int o = tid * 16;
#pragma unroll
      for (int r = 0; r < 4; ++r) stage16(src + o + r*8192, dst + o + r*8192);
    }
    __builtin_amdgcn_s_setprio(1);
    const int abuf = (p >> 2) & 1;
    const int slotb = (j & 1)*4 + 2*mp;
#pragma unroll
    for (int nt = 0; nt < 4; ++nt)
#pragma unroll
      for (int i = 0; i < 2; ++i)
        S[nt][slotb + i] = mfma16(af[abuf][nt], kf[cur][i], S[nt][slotb + i]);
    __builtin_amdgcn_s_setprio(0);
    S_BARRIER();
  }

  // stage V chunk 0,1 -> ring0,ring1 (hidden under softmax)
  {
    int o = tid * 16;
#pragma unroll
    for (int r = 0; r < 4; ++r) stage16(vBb + o + r*8192, ring + o + r*8192);
#pragma unroll
    for (int r = 0; r < 4; ++r) stage16(vBb + 32768 + o + r*8192, ring + 32768 + o + r*8192);
  }

  // ---- Phase C: softmax; fold 1/rowsum into P ----
  {
    float M[4][4];
#pragma unroll
    for (int nt = 0; nt < 4; ++nt)
#pragma unroll
      for (int r = 0; r < 4; ++r) {
        float m = S[nt][0][r];
#pragma unroll
        for (int ms = 1; ms < 8; ++ms) m = fmaxf(m, S[nt][ms][r]);
#pragma unroll
        for (int d = 1; d < 16; d <<= 1) m = fmaxf(m, __shfl_xor(m, d));
        M[nt][r] = m;
      }
    if (l15 == 0)
#pragma unroll
      for (int nt = 0; nt < 4; ++nt)
#pragma unroll
        for (int r = 0; r < 4; ++r) smax[w][16*nt + 4*q + r] = M[nt][r];
    WAIT_LGKM0();
    S_BARRIER();
#pragma unroll
    for (int nt = 0; nt < 4; ++nt)
#pragma unroll
      for (int r = 0; r < 4; ++r) {
        int n = 16*nt + 4*q + r;
        float m = smax[0][n];
#pragma unroll
        for (int w2 = 1; w2 < 8; ++w2) m = fmaxf(m, smax[w2][n]);
        M[nt][r] = m;
      }
    float sm[4][4] = {};
#pragma unroll
    for (int nt = 0; nt < 4; ++nt)
#pragma unroll
      for (int ms = 0; ms < 8; ++ms)
#pragma unroll
        for (int r = 0; r < 4; ++r) {
          float p = __expf(S[nt][ms][r] - M[nt][r]);
          S[nt][ms][r] = p;
          sm[nt][r] += p;
        }
#pragma unroll
    for (int nt = 0; nt < 4; ++nt)
#pragma unroll
      for (int r = 0; r < 4; ++r)
#pragma unroll
        for (int d = 1; d < 16; d <<= 1) sm[nt][r] += __shfl_xor(sm[nt][r], d);
    if (l15 == 0)
#pragma unroll
      for (int nt = 0; nt < 4; ++nt)
#pragma unroll
        for (int r = 0; r < 4; ++r) ssum[w][16*nt + 4*q + r] = sm[nt][r];
    WAIT_LGKM0();
    S_BARRIER();
#pragma unroll
    for (int nt = 0; nt < 4; ++nt)
#pragma unroll
      for (int r = 0; r < 4; ++r) {
        int n = 16*nt + 4*q + r;
        float s = ssum[0][n];
#pragma unroll
        for (int w2 = 1; w2 < 8; ++w2) s += ssum[w2][n];
        float iv = 1.0f / s;
#pragma unroll
        for (int ms = 0; ms < 8; ++ms) S[nt][ms][r] *= iv;
      }
  }

  // P chunk writer: chunk ch owned by wave ch&7, slots (ch>>3)*4 ..
  auto writeP = [&](int ch, char* dst) {
    if (w == (ch & 7)) {
      int msb = (ch >> 3) * 4;
#pragma unroll
      for (int nt = 0; nt < 4; ++nt)
#pragma unroll
        for (int mt = 0; mt < 4; ++mt)
#pragma unroll
          for (int r = 0; r < 4; ++r) {
            int n = 16*nt + 4*q + r;
            int mi = 16*mt + l15;
            *(f16*)(dst + n*128 + (((mi >> 3) ^ (n & 7)) << 4) + ((mi & 7) << 1)) = (f16)S[nt][msb + mt][r];
          }
    }
  };

  writeP(0, bufQ);     // q dead; region reused as P dbuf
  WAIT_LGKM0();
  S_BARRIER();

  // ---- Phase D: O += P.V, 32 phases, 8-MFMA clusters ----
  WAIT_VM(4);          // V chunk0 LDS-complete
  f16x8 pa[2][4], vf[2][2];
#pragma unroll
  for (int nt = 0; nt < 4; ++nt) {
    int n = 16*nt + l15;
    pa[0][nt] = *(const f16x8*)(bufQ + n*128 + ((q ^ (n & 7)) << 4));
  }
#pragma unroll
  for (int ct = 0; ct < 2; ++ct) {
    int c = 32*w + 16*ct + l15;
    vf[0][ct] = *(const f16x8*)(ring + c*128 + ((q ^ (c & 7)) << 4));
  }
  f32x4 O[4][2] = {};
#pragma unroll
  for (int p = 0; p < 32; ++p) {
    const int ch = p >> 1, k2 = p & 1, cur = p & 1, nxt = cur ^ 1;
    if (p & 1) WAIT_VM(4);   // V chunk ch+1 LDS-complete
    if (p < 31) {
      const int p1 = p + 1, ch2 = p1 >> 1, k22 = p1 & 1;
      const char* pc = bufQ + (ch2 & 1)*8192;
#pragma unroll
      for (int nt = 0; nt < 4; ++nt) {
        int n = 16*nt + l15;
        pa[nxt][nt] = *(const f16x8*)(pc + n*128 + (((4*k22 + q) ^ (n & 7)) << 4));
      }
      const char* vc = ring + (ch2 % 3)*32768;
#pragma unroll
      for (int ct = 0; ct < 2; ++ct) {
        int c = 32*w + 16*ct + l15;
        vf[nxt][ct] = *(const f16x8*)(vc + c*128 + (((4*k22 + q) ^ (c & 7)) << 4));
      }
    }
    bool wrote = false;
    if (k2 == 0 && ch + 2 < 16) {
      const char* src = vBb + (size_t)(ch + 2)*32768;
      char* dst = ring + ((ch + 2) % 3)*32768;
      int o = tid * 16;
#pragma unroll
      for (int r = 0; r < 4; ++r) stage16(src + o + r*8192, dst + o + r*8192);
    }
    if (k2 == 0 && ch + 1 < 16) { writeP(ch + 1, bufQ + ((ch + 1) & 1)*8192); wrote = true; }
    __builtin_amdgcn_s_setprio(1);
#pragma unroll
    for (int nt = 0; nt < 4; ++nt)
#pragma unroll
      for (int ct = 0; ct < 2; ++ct)
        O[nt][ct] = mfma16(pa[cur][nt], vf[cur][ct], O[nt][ct]);
    __builtin_amdgcn_s_setprio(0);
    if (wrote) WAIT_LGKM0();
    S_BARRIER();
  }

  // ---- Phase E: out = gamma*O + x ----
  float g = gamma_p[0];
#pragma unroll
  for (int nt = 0; nt < 4; ++nt)
#pragma unroll
    for (int ct = 0; ct < 2; ++ct) {
      int c = 32*w + 16*ct + l15;
      size_t base = (size_t)(b*CDIM + c)*NPIX + n0 + 16*nt + 4*q;
      f32x4 xv = *(const f32x4*)(x + base);
      f32x4 ov;
#pragma unroll
      for (int r = 0; r < 4; ++r) ov[r] = g * O[nt][ct][r] + xv[r];
      *(f32x4*)(out + base) = ov;
    }
}

extern "C" void kernel_launch(void* const* d_in, const int* in_sizes, int n_in,
                              void* d_out, int out_size, void* d_ws, size_t ws_size,
                              hipStream_t stream) {
  (void)in_sizes; (void)n_in; (void)out_size; (void)ws_size;
  const float* x     = (const float*)d_in[0];
  const float* Wq    = (const float*)d_in[1];
  const float* bq    = (const float*)d_in[2];
  const float* Wk    = (const float*)d_in[3];
  const float* bk    = (const float*)d_in[4];
  const float* Wv    = (const float*)d_in[5];
  const float* bv    = (const float*)d_in[6];
  const float* Ws    = (const float*)d_in[7];
  const float* bs    = (const float*)d_in[8];
  const float* gamma = (const float*)d_in[9];

  char* ws = (char*)d_ws;
  float* bk2 = (float*)(ws);
  float* bv2 = (float*)(ws + 1024);
  char* xT   = ws + 4096;
  char* kB   = ws + 4096 + 37748736;
  char* vB   = kB + 4194304;
  f16* WqF   = (f16*)(vB + 4194304);
  f16* Wk2H  = WqF + 65536;
  f16* Wv2H  = Wk2H + 65536;

  prep_weights<<<256, 256, 0, stream>>>(Wq, Wk, bk, Wv, bv, Ws, bs, WqF, Wk2H, Wv2H, bk2, bv2);
  transpose_x<<<dim3(8, 288, 8), dim3(32, 8), 0, stream>>>(x, xT);
  compute_kv<<<dim3(32, 8), 256, 0, stream>>>(xT, Wk2H, Wv2H, bk2, bv2, kB, vB);
  attention<<<1152, 512, 0, stream>>>(xT, WqF, bq, kB, vB, x, gamma, (float*)d_out);
}